// Round 5
// baseline (768.228 us; speedup 1.0000x reference)
//
#include <hip/hip_runtime.h>
#include <stdint.h>

typedef unsigned short u16;
typedef __bf16 bf16x8 __attribute__((ext_vector_type(8)));
typedef float f32x4 __attribute__((ext_vector_type(4)));

// Geometry
// x: [8, 512, 100, 100] NCHW (dtype runtime-detected: f32 or bf16). Padded grid 102x102.
// xt: channels-last padded input [b][row][c] bf16, row = 128-guard + p, per-batch stride 10752 rows.
// feat: [b][p][o] bf16, per-batch stride 10496 rows.
// wA: [o][cchunk*576 + s*64 + c_in]  (K-order: c-chunk major, shift s, 64 c_in)
#define XT_STRIDE 10752
#define XT_GUARD  128
#define NPAD      10496
#define NT        82

__device__ __forceinline__ float b2f(u16 u) {
  union { unsigned int i; float f; } v; v.i = ((unsigned int)u) << 16; return v.f;
}
__device__ __forceinline__ u16 f2b(float f) {
  union { float f; unsigned int i; } v; v.f = f;
  unsigned int u = v.i;
  unsigned int r = u + 0x7FFFu + ((u >> 16) & 1u);  // RNE, finite inputs
  return (u16)(r >> 16);
}
__device__ __forceinline__ float ldin(const void* p, long i, int f32) {
  return f32 ? ((const float*)p)[i] : b2f(((const u16*)p)[i]);
}
// async global->LDS, 16B per lane; LDS dest = wave-uniform base + lane*16
__device__ __forceinline__ void async16(const void* g, void* l) {
  __builtin_amdgcn_global_load_lds(
      (const __attribute__((address_space(1))) unsigned int*)g,
      (__attribute__((address_space(3))) unsigned int*)l, 16, 0, 0);
}
// Wave-level dtype sniff: all waves scan the SAME 16KB window of x -> identical verdict.
__device__ __forceinline__ int sniff_is_f32(const void* x) {
  const uint4* p = (const uint4*)x;
  const int lane = threadIdx.x & 63;
  unsigned int acc = 0;
  #pragma unroll
  for (int i = 0; i < 16; ++i) {
    uint4 v = p[i * 64 + lane];
    unsigned int w0 = v.x, w1 = v.y, w2 = v.z, w3 = v.w;
    acc |= ((w0 & 0x7F80u) == 0x7F80u) | (((w0 >> 16) & 0x7F80u) == 0x7F80u);
    acc |= ((w1 & 0x7F80u) == 0x7F80u) | (((w1 >> 16) & 0x7F80u) == 0x7F80u);
    acc |= ((w2 & 0x7F80u) == 0x7F80u) | (((w2 >> 16) & 0x7F80u) == 0x7F80u);
    acc |= ((w3 & 0x7F80u) == 0x7F80u) | (((w3 >> 16) & 0x7F80u) == 0x7F80u);
  }
  return __any(acc != 0) ? 1 : 0;
}

// ---------------- k_prep: fused zero-pads + transpose + wA-shuffle + wH/bias pack ----------------
// Roles by block range (independent, disjoint writes):
//   [0,6400): transpose  (b 8 x h 100 x cb 8)
//   [6400,7904): zero xt pad/guard cells (8 x 188)
//   [7904,8928): wA shuffle (1024)
//   [8928,9024): wH + biases (96); block 8928 publishes dtype flag for k_head
__global__ __launch_bounds__(256) void k_prep(const void* __restrict__ x,
                                              const void* __restrict__ w_rpn,
                                              const void* __restrict__ b_rpn,
                                              const void* __restrict__ w_cls,
                                              const void* __restrict__ b_cls,
                                              const void* __restrict__ w_bbox,
                                              const void* __restrict__ b_bbox,
                                              u16* __restrict__ xt,
                                              u16* __restrict__ wA,
                                              u16* __restrict__ wH,
                                              float* __restrict__ bAll,
                                              int* __restrict__ flagOut) {
  const int blk = blockIdx.x;
  const int t = threadIdx.x;
  if (blk < 6400) {
    // ---- transpose: unit = 8 channels x 4 w; reg transpose, 16B stores ----
    const int f32 = sniff_is_f32(x);
    if (t >= 200) return;
    const int b = blk / 800, r = blk - b * 800;
    const int h = r >> 3, cb = r & 7;
    const int co = t / 25, jw = t % 25;
    const int c0 = cb * 64 + co * 8;
    u16 v[8][4];
    if (!f32) {
      const u16* src = (const u16*)x + (long)(b * 512 + c0) * 10000 + h * 100 + jw * 4;
      #pragma unroll
      for (int dc = 0; dc < 8; ++dc) {
        uint2 u = *(const uint2*)(src + (long)dc * 10000);
        const u16* pv = (const u16*)&u;
        v[dc][0] = pv[0]; v[dc][1] = pv[1]; v[dc][2] = pv[2]; v[dc][3] = pv[3];
      }
    } else {
      const float* src = (const float*)x + (long)(b * 512 + c0) * 10000 + h * 100 + jw * 4;
      #pragma unroll
      for (int dc = 0; dc < 8; ++dc) {
        float4 u = *(const float4*)(src + (long)dc * 10000);
        v[dc][0] = f2b(u.x); v[dc][1] = f2b(u.y); v[dc][2] = f2b(u.z); v[dc][3] = f2b(u.w);
      }
    }
    u16* dst = xt + ((long)b * XT_STRIDE + XT_GUARD + (h + 1) * 102 + 1 + jw * 4) * 512 + c0;
    #pragma unroll
    for (int dw = 0; dw < 4; ++dw) {
      union { uint4 u; u16 s[8]; } pk;
      #pragma unroll
      for (int dc = 0; dc < 8; ++dc) pk.s[dc] = v[dc][dw];
      *(uint4*)(dst + (long)dw * 512) = pk.u;
    }
  } else if (blk < 7904) {
    // ---- zero pad/guard cells of xt (48128 uint4 units per batch) ----
    const int i2 = blk - 6400;
    const int b = i2 / 188, bx = i2 - b * 188;
    const int i = bx * 256 + t;
    if (i >= 48128) return;
    int row, sub;
    if (i < 35328) {
      int rr = i >> 6; sub = i & 63;
      row = (rr < 230) ? rr : (10200 + rr);  // [0,230) or [10430,10752)
    } else {
      int j = i - 35328;
      int ci = j >> 6; sub = j & 63;
      int pr = (ci >> 1) + 1;
      row = XT_GUARD + pr * 102 + (ci & 1) * 101;
    }
    uint4 z = {0, 0, 0, 0};
    *(uint4*)(xt + ((long)b * XT_STRIDE + row) * 512 + sub * 8) = z;
  } else if (blk < 8928) {
    // ---- wA: [o][c][3][3] -> [o][cchunk*576 + s*64 + c_in]  (s-fastest K order) ----
    const int f32 = sniff_is_f32(x);
    const int idx = (blk - 7904) * 256 + t;     // o*512+c
    const int o = idx >> 9, c = idx & 511;
    u16* dst = wA + (long)o * 4608 + (c >> 6) * 576 + (c & 63);
    #pragma unroll
    for (int s = 0; s < 9; ++s) dst[s * 64] = f2b(ldin(w_rpn, (long)idx * 9 + s, f32));
  } else {
    // ---- wH [48][512] (45 real + 3 zero rows) + biases + flag publish ----
    const int f32 = sniff_is_f32(x);
    const int idx = (blk - 8928) * 256 + t;     // < 24576
    const int a = idx >> 9, c = idx & 511;
    float v = 0.f;
    if (a < 9) v = ldin(w_cls, a * 512 + c, f32);
    else if (a < 45) v = ldin(w_bbox, (a - 9) * 512 + c, f32);
    wH[idx] = f2b(v);
    if (idx < 512) bAll[idx] = ldin(b_rpn, idx, f32);
    if (c == 0) {
      float bv = 0.f;
      if (a < 9) bv = ldin(b_cls, a, f32);
      else if (a < 45) bv = ldin(b_bbox, a - 9, f32);
      bAll[512 + a] = bv;
    }
    if (blk == 8928 && t == 0) *flagOut = f32;
  }
}

// ---------------- Conv implicit GEMM: 128x128 tile, BK=64, PREFETCH double-buffer ----------------
// Geometry/layout = the 366us champion (16x16x32 MFMA, l15-row + XOR-seg conflict-free LDS,
// s-fastest K for L2-resident B, XCD swizzle, 4 waves x 64x64). Structural change only:
//   champion:  stage(ks) -> vmcnt(0) -> barrier -> MFMA -> barrier     (drain fully EXPOSED)
//   this:      stage(ks+1)->buf^1 -> ds_read/MFMA buf -> barrier(+implicit vmcnt0 drain)
// The drain now waits on loads issued ~400-600 cy earlier (under 16 ds_read + 32 MFMA), so the
// L2-hit staging latency is hidden in-block instead of relying on co-resident blocks.
// Calibration (R0/R3 counters): MFMA demand = 4.85 cyc/CU per mfma -> champion wall 878K cyc vs
// 458K MFMA = 52% (matches measured 52.5). Removing the exposed drain targets wall ~550-650K cyc.
// Hazards (1 barrier/iter): buf[cur] reads complete before barrier (consumed by MFMA, lgkm
// drained at barrier); stage into buf[cur] happens only in the NEXT iteration, after that
// barrier; buf^1 writes are vmcnt(0)-drained at the same barrier before next iter reads.
// LDS: 2x(16+16) KB + bias = 66 KB -> 2 blocks/CU; grid 2624 -> 5.1 scheduling rounds.
__global__ __launch_bounds__(256, 2) void k_conv(const u16* __restrict__ xt, const u16* __restrict__ wA,
                                                 const float* __restrict__ bAll, u16* __restrict__ feat) {
  __shared__ u16 sA[2][128 * 64];   // 2 x 16 KB
  __shared__ u16 sB[2][128 * 64];   // 2 x 16 KB
  __shared__ float sBias[128];
  const int t = threadIdx.x;
  const int i = blockIdx.x;            // 0..2623
  const int xcd = i & 7, j = i >> 3;   // j: 0..327
  const int mtb = j / 82, nt = j - mtb * 82;
  const int pair = xcd + 8 * mtb;      // 0..31
  const int mt = pair & 3, b = pair >> 2;
  const int m0 = mt * 128, n0 = nt * 128;
  if (t < 128) sBias[t] = bAll[m0 + t];
  f32x4 acc[4][4] = {};
  const int lane = t & 63, wv = t >> 6;
  const int srow = t >> 3;                              // staging row 0..31 (+32 per round)
  const int sseg = (((t & 7) ^ (srow & 7))) * 8;        // XOR-permuted source segment
  const int mh = (wv & 1) * 64, nh = (wv >> 1) * 64;
  const int l15 = lane & 15, q = lane >> 4;
  const int s7 = l15 & 7;                               // reader XOR key (row&7)
  const u16* gA = wA + (long)(m0 + srow) * 4608 + sseg;
  const u16* xtb = xt + ((long)b * XT_STRIDE + XT_GUARD) * 512;

  auto stage = [&](int ks, int buf) {
    const int k0 = ks * 64;
    const int cchunk = ks / 9;
    const int s = ks - cchunk * 9;                      // shift 0..8, FASTEST
    const int c0 = cchunk * 64;
    const int off = (s / 3) * 102 + (s - (s / 3) * 3) - 103;  // (dh-1)*102 + (dw-1)
    const u16* gB = xtb + (long)(n0 + srow + off) * 512 + c0 + sseg;
    u16* sAw = sA[buf] + wv * 512;                      // wave staging base (1KB/wave)
    u16* sBw = sB[buf] + wv * 512;
    async16(gA + k0,                  sAw);
    async16(gA + k0 + (long)32 * 4608, sAw + 32 * 64);
    async16(gA + k0 + (long)64 * 4608, sAw + 64 * 64);
    async16(gA + k0 + (long)96 * 4608, sAw + 96 * 64);
    async16(gB,             sBw);
    async16(gB + 32 * 512,  sBw + 32 * 64);
    async16(gB + 64 * 512,  sBw + 64 * 64);
    async16(gB + 96 * 512,  sBw + 96 * 64);
  };

  // prologue: tile 0 into buf 0, full drain once
  stage(0, 0);
  asm volatile("s_waitcnt vmcnt(0)" ::: "memory");
  __syncthreads();

  for (int ks = 0; ks < 72; ++ks) {
    const int cur = ks & 1;
    if (ks < 71) stage(ks + 1, cur ^ 1);               // prefetch: issue BEFORE compute
    const u16* rowA = sA[cur] + (mh + l15) * 64;
    const u16* rowB = sB[cur] + (nh + l15) * 64;
    __builtin_amdgcn_s_setprio(1);
    #pragma unroll
    for (int h = 0; h < 2; ++h) {
      const int segA = ((h * 4 + q) ^ s7) * 8;          // un-swizzle: seg idx h*4+q
      bf16x8 af[4], bf[4];
      #pragma unroll
      for (int mi = 0; mi < 4; ++mi) af[mi] = *(const bf16x8*)(rowA + mi * 1024 + segA);
      #pragma unroll
      for (int ni = 0; ni < 4; ++ni) bf[ni] = *(const bf16x8*)(rowB + ni * 1024 + segA);
      #pragma unroll
      for (int mi = 0; mi < 4; ++mi)
        #pragma unroll
        for (int ni = 0; ni < 4; ++ni)
          acc[mi][ni] = __builtin_amdgcn_mfma_f32_16x16x32_bf16(af[mi], bf[ni], acc[mi][ni], 0, 0, 0);
    }
    __builtin_amdgcn_s_setprio(0);
    __syncthreads();   // implicit vmcnt(0)+lgkmcnt(0): drains prefetch issued ~600cy earlier
  }

  u16* fb = feat + (long)b * NPAD * 512;
  #pragma unroll
  for (int mi = 0; mi < 4; ++mi) {
    const int ol = mh + mi * 16 + q * 4;
    #pragma unroll
    for (int ni = 0; ni < 4; ++ni) {
      const int p = n0 + nh + ni * 16 + l15;
      unsigned long long pk = 0;
      #pragma unroll
      for (int r = 0; r < 4; ++r) {
        float v = acc[mi][ni][r] + sBias[ol + r];
        v = v > 0.f ? v : 0.f;
        pk |= ((unsigned long long)f2b(v)) << (16 * r);
      }
      *(unsigned long long*)(fb + (long)p * 512 + m0 + ol) = pk;
    }
  }
}

// ---------------- k_head: LDS-free MFMA, dual-dtype store (flag from ws) ----------------
__global__ __launch_bounds__(256) void k_head(const u16* __restrict__ feat, const u16* __restrict__ wH,
                                              const float* __restrict__ bAll, void* __restrict__ out,
                                              const int* __restrict__ flag) {
  const int f32 = *flag;
  const int t = threadIdx.x;
  const int lane = t & 63, wv = t >> 6;
  const int l15 = lane & 15, q = lane >> 4;
  const int slot = blockIdx.x * 64 + wv * 16;          // 64 p-slots per block; NPAD%64==0
  const int b = slot / NPAD, p0 = slot - b * NPAD;
  const u16* fp = feat + ((long)b * NPAD + p0 + l15) * 512 + q * 8;
  const u16* ap = wH + (long)l15 * 512 + q * 8;
  f32x4 acc[3] = {};
  #pragma unroll
  for (int ks = 0; ks < 16; ++ks) {
    const int k0 = ks * 32;
    bf16x8 bf = *(const bf16x8*)(fp + k0);
    bf16x8 a0 = *(const bf16x8*)(ap + k0);
    bf16x8 a1 = *(const bf16x8*)(ap + 16 * 512 + k0);
    bf16x8 a2 = *(const bf16x8*)(ap + 32 * 512 + k0);
    acc[0] = __builtin_amdgcn_mfma_f32_16x16x32_bf16(a0, bf, acc[0], 0, 0, 0);
    acc[1] = __builtin_amdgcn_mfma_f32_16x16x32_bf16(a1, bf, acc[1], 0, 0, 0);
    acc[2] = __builtin_amdgcn_mfma_f32_16x16x32_bf16(a2, bf, acc[2], 0, 0, 0);
  }
  const int p = p0 + l15;
  const int pr = p / 102, pc = p - pr * 102;
  if (pr < 1 || pr > 100 || pc < 1 || pc > 100) return;  // pad position
  const int h = pr - 1, w = pc - 1;
  #pragma unroll
  for (int mi = 0; mi < 3; ++mi) {
    #pragma unroll
    for (int r = 0; r < 4; ++r) {
      const int a = mi * 16 + q * 4 + r;
      if (a >= 45) continue;
      float v = acc[mi][r] + bAll[512 + a];
      long oidx;
      if (a < 9) oidx = ((long)(b * 9 + a)) * 10000 + h * 100 + w;
      else       oidx = 720000 + ((long)(b * 36 + (a - 9))) * 10000 + h * 100 + w;
      if (f32) ((float*)out)[oidx] = v;
      else     ((u16*)out)[oidx] = f2b(v);
    }
  }
}

extern "C" void kernel_launch(void* const* d_in, const int* in_sizes, int n_in,
                              void* d_out, int out_size, void* d_ws, size_t ws_size,
                              hipStream_t stream) {
  const void* x      = d_in[0];
  const void* w_rpn  = d_in[1];
  const void* b_rpn  = d_in[2];
  const void* w_cls  = d_in[3];
  const void* b_cls  = d_in[4];
  const void* w_bbox = d_in[5];
  const void* b_bbox = d_in[6];
  char* ws = (char*)d_ws;
  u16*  xt   = (u16*) (ws);                 // 8*10752*512*2 = 88,080,384
  u16*  feat = (u16*) (ws + 88080384);      // 8*10496*512*2 = 85,983,232
  u16*  wA   = (u16*) (ws + 174063616);     // 512*4608*2    =  4,718,592
  u16*  wH   = (u16*) (ws + 178782208);     // 48*512*2      =     49,152
  float* bAll= (float*)(ws + 178831360);    // 560*4
  int*  flag = (int*) (ws + 178833600);     // 4

  k_prep<<<9024, 256, 0, stream>>>(x, w_rpn, b_rpn, w_cls, b_cls, w_bbox, b_bbox,
                                   xt, wA, wH, bAll, flag);
  k_conv<<<2624, 256, 0, stream>>>(xt, wA, bAll, feat);
  k_head<<<1312, 256, 0, stream>>>(feat, wH, bAll, d_out, flag);
}

// Round 6
// 763.804 us; speedup vs baseline: 1.0058x; 1.0058x over previous
//
#include <hip/hip_runtime.h>
#include <stdint.h>

typedef unsigned short u16;
typedef __bf16 bf16x8 __attribute__((ext_vector_type(8)));
typedef float f32x4 __attribute__((ext_vector_type(4)));

// Geometry
// x: [8, 512, 100, 100] NCHW (dtype runtime-detected: f32 or bf16). Padded grid 102x102.
// xt: channels-last padded input [b][row][c] bf16, row = 128-guard + p, per-batch stride 10752 rows.
// feat: [b][p][o] bf16, per-batch stride 10496 rows.
// wA: [o][cchunk*576 + s*64 + c_in]  (K-order: c-chunk major, shift s, 64 c_in)
#define XT_STRIDE 10752
#define XT_GUARD  128
#define NPAD      10496
#define NT        82

__device__ __forceinline__ float b2f(u16 u) {
  union { unsigned int i; float f; } v; v.i = ((unsigned int)u) << 16; return v.f;
}
__device__ __forceinline__ u16 f2b(float f) {
  union { float f; unsigned int i; } v; v.f = f;
  unsigned int u = v.i;
  unsigned int r = u + 0x7FFFu + ((u >> 16) & 1u);  // RNE, finite inputs
  return (u16)(r >> 16);
}
__device__ __forceinline__ float ldin(const void* p, long i, int f32) {
  return f32 ? ((const float*)p)[i] : b2f(((const u16*)p)[i]);
}
// async global->LDS, 16B per lane; LDS dest = wave-uniform base + lane*16
__device__ __forceinline__ void async16(const void* g, void* l) {
  __builtin_amdgcn_global_load_lds(
      (const __attribute__((address_space(1))) unsigned int*)g,
      (__attribute__((address_space(3))) unsigned int*)l, 16, 0, 0);
}
// Wave-level dtype sniff: all waves scan the SAME 16KB window of x -> identical verdict.
__device__ __forceinline__ int sniff_is_f32(const void* x) {
  const uint4* p = (const uint4*)x;
  const int lane = threadIdx.x & 63;
  unsigned int acc = 0;
  #pragma unroll
  for (int i = 0; i < 16; ++i) {
    uint4 v = p[i * 64 + lane];
    unsigned int w0 = v.x, w1 = v.y, w2 = v.z, w3 = v.w;
    acc |= ((w0 & 0x7F80u) == 0x7F80u) | (((w0 >> 16) & 0x7F80u) == 0x7F80u);
    acc |= ((w1 & 0x7F80u) == 0x7F80u) | (((w1 >> 16) & 0x7F80u) == 0x7F80u);
    acc |= ((w2 & 0x7F80u) == 0x7F80u) | (((w2 >> 16) & 0x7F80u) == 0x7F80u);
    acc |= ((w3 & 0x7F80u) == 0x7F80u) | (((w3 >> 16) & 0x7F80u) == 0x7F80u);
  }
  return __any(acc != 0) ? 1 : 0;
}

// ---------------- k_prep: fused zero-pads + transpose + wA-shuffle + wH/bias pack ----------------
// Roles by block range (independent, disjoint writes):
//   [0,6400): transpose  (b 8 x h 100 x cb 8)
//   [6400,7904): zero xt pad/guard cells (8 x 188)
//   [7904,8928): wA shuffle (1024)
//   [8928,9024): wH + biases (96); block 8928 publishes dtype flag for k_head
__global__ __launch_bounds__(256) void k_prep(const void* __restrict__ x,
                                              const void* __restrict__ w_rpn,
                                              const void* __restrict__ b_rpn,
                                              const void* __restrict__ w_cls,
                                              const void* __restrict__ b_cls,
                                              const void* __restrict__ w_bbox,
                                              const void* __restrict__ b_bbox,
                                              u16* __restrict__ xt,
                                              u16* __restrict__ wA,
                                              u16* __restrict__ wH,
                                              float* __restrict__ bAll,
                                              int* __restrict__ flagOut) {
  const int blk = blockIdx.x;
  const int t = threadIdx.x;
  if (blk < 6400) {
    // ---- transpose: unit = 8 channels x 4 w; reg transpose, 16B stores ----
    const int f32 = sniff_is_f32(x);
    if (t >= 200) return;
    const int b = blk / 800, r = blk - b * 800;
    const int h = r >> 3, cb = r & 7;
    const int co = t / 25, jw = t % 25;
    const int c0 = cb * 64 + co * 8;
    u16 v[8][4];
    if (!f32) {
      const u16* src = (const u16*)x + (long)(b * 512 + c0) * 10000 + h * 100 + jw * 4;
      #pragma unroll
      for (int dc = 0; dc < 8; ++dc) {
        uint2 u = *(const uint2*)(src + (long)dc * 10000);
        const u16* pv = (const u16*)&u;
        v[dc][0] = pv[0]; v[dc][1] = pv[1]; v[dc][2] = pv[2]; v[dc][3] = pv[3];
      }
    } else {
      const float* src = (const float*)x + (long)(b * 512 + c0) * 10000 + h * 100 + jw * 4;
      #pragma unroll
      for (int dc = 0; dc < 8; ++dc) {
        float4 u = *(const float4*)(src + (long)dc * 10000);
        v[dc][0] = f2b(u.x); v[dc][1] = f2b(u.y); v[dc][2] = f2b(u.z); v[dc][3] = f2b(u.w);
      }
    }
    u16* dst = xt + ((long)b * XT_STRIDE + XT_GUARD + (h + 1) * 102 + 1 + jw * 4) * 512 + c0;
    #pragma unroll
    for (int dw = 0; dw < 4; ++dw) {
      union { uint4 u; u16 s[8]; } pk;
      #pragma unroll
      for (int dc = 0; dc < 8; ++dc) pk.s[dc] = v[dc][dw];
      *(uint4*)(dst + (long)dw * 512) = pk.u;
    }
  } else if (blk < 7904) {
    // ---- zero pad/guard cells of xt (48128 uint4 units per batch) ----
    const int i2 = blk - 6400;
    const int b = i2 / 188, bx = i2 - b * 188;
    const int i = bx * 256 + t;
    if (i >= 48128) return;
    int row, sub;
    if (i < 35328) {
      int rr = i >> 6; sub = i & 63;
      row = (rr < 230) ? rr : (10200 + rr);  // [0,230) or [10430,10752)
    } else {
      int j = i - 35328;
      int ci = j >> 6; sub = j & 63;
      int pr = (ci >> 1) + 1;
      row = XT_GUARD + pr * 102 + (ci & 1) * 101;
    }
    uint4 z = {0, 0, 0, 0};
    *(uint4*)(xt + ((long)b * XT_STRIDE + row) * 512 + sub * 8) = z;
  } else if (blk < 8928) {
    // ---- wA: [o][c][3][3] -> [o][cchunk*576 + s*64 + c_in]  (s-fastest K order) ----
    const int f32 = sniff_is_f32(x);
    const int idx = (blk - 7904) * 256 + t;     // o*512+c
    const int o = idx >> 9, c = idx & 511;
    u16* dst = wA + (long)o * 4608 + (c >> 6) * 576 + (c & 63);
    #pragma unroll
    for (int s = 0; s < 9; ++s) dst[s * 64] = f2b(ldin(w_rpn, (long)idx * 9 + s, f32));
  } else {
    // ---- wH [48][512] (45 real + 3 zero rows) + biases + flag publish ----
    const int f32 = sniff_is_f32(x);
    const int idx = (blk - 8928) * 256 + t;     // < 24576
    const int a = idx >> 9, c = idx & 511;
    float v = 0.f;
    if (a < 9) v = ldin(w_cls, a * 512 + c, f32);
    else if (a < 45) v = ldin(w_bbox, (a - 9) * 512 + c, f32);
    wH[idx] = f2b(v);
    if (idx < 512) bAll[idx] = ldin(b_rpn, idx, f32);
    if (c == 0) {
      float bv = 0.f;
      if (a < 9) bv = ldin(b_cls, a, f32);
      else if (a < 45) bv = ldin(b_bbox, a - 9, f32);
      bAll[512 + a] = bv;
    }
    if (blk == 8928 && t == 0) *flagOut = f32;
  }
}

// ---------------- Conv implicit GEMM: 128x128 tile, BK=64, depth-2 counted-vmcnt pipeline ----------------
// Geometry/layout = the 366us champion (16x16x32 MFMA, l15-row + XOR-seg conflict-free LDS,
// s-fastest K for L2-resident B, XCD swizzle, 4 waves x 64x64). Pipeline change (T4, AITER-style):
//   champion: stage(ks) -> vmcnt(0) -> barrier -> MFMA -> barrier      (drain EXPOSED; convoy:
//             delivery 2340cy + MFMA 2480cy serialize -> predicted 51.5% util vs 52.5 measured)
//   R5:       prefetch + __syncthreads -> STILL vmcnt(0), distance ~1 cluster -> exposed (34%)
//   this:     prologue stages tiles 0,1; per iter: vmcnt(8) [waits tile ks only, tile ks+1 stays
//             in flight] -> raw s_barrier -> MFMA on buf[ks&1] -> raw s_barrier -> stage(ks+2).
// Issue->wait distance = 2 full steps (~2500cy) => loads pre-landed, wave never idles on VMEM.
// NEVER vmcnt(0) in-loop (only tail ks=71). Raw s_barrier (no implicit drain) + asm memory fences
// (pattern HW-validated for correctness in R1).
// Hazards: per-wave vmcnt(8)+barrier => ALL waves' tile-ks loads landed before any read; restage
// of buf[cur] only after post-read barrier; a wave's ds_reads complete before its MFMAs (compiler
// lgkm) hence before barrier arrival.
// LDS 2x(16+16)KB + bias = 66KB -> 2 blocks/CU; delivery 1170cy/step < MFMA 1240cy/step per CU,
// so MFMA stays fed even at 2 blocks.
__global__ __launch_bounds__(256, 2) void k_conv(const u16* __restrict__ xt, const u16* __restrict__ wA,
                                                 const float* __restrict__ bAll, u16* __restrict__ feat) {
  __shared__ u16 sA[2][128 * 64];   // 2 x 16 KB
  __shared__ u16 sB[2][128 * 64];   // 2 x 16 KB
  __shared__ float sBias[128];
  const int t = threadIdx.x;
  const int i = blockIdx.x;            // 0..2623
  const int xcd = i & 7, j = i >> 3;   // j: 0..327
  const int mtb = j / 82, nt = j - mtb * 82;
  const int pair = xcd + 8 * mtb;      // 0..31
  const int mt = pair & 3, b = pair >> 2;
  const int m0 = mt * 128, n0 = nt * 128;
  if (t < 128) sBias[t] = bAll[m0 + t];
  f32x4 acc[4][4] = {};
  const int lane = t & 63, wv = t >> 6;
  const int srow = t >> 3;                              // staging row 0..31 (+32 per round)
  const int sseg = (((t & 7) ^ (srow & 7))) * 8;        // XOR-permuted source segment
  const int mh = (wv & 1) * 64, nh = (wv >> 1) * 64;
  const int l15 = lane & 15, q = lane >> 4;
  const int s7 = l15 & 7;                               // reader XOR key (row&7)
  const u16* gA = wA + (long)(m0 + srow) * 4608 + sseg;
  const u16* xtb = xt + ((long)b * XT_STRIDE + XT_GUARD) * 512;

  auto stage = [&](int ks, int buf) {                   // 8 async16 per wave, 32KB per block
    const int k0 = ks * 64;
    const int cchunk = ks / 9;
    const int s = ks - cchunk * 9;                      // shift 0..8, FASTEST
    const int c0 = cchunk * 64;
    const int off = (s / 3) * 102 + (s - (s / 3) * 3) - 103;  // (dh-1)*102 + (dw-1)
    const u16* gB = xtb + (long)(n0 + srow + off) * 512 + c0 + sseg;
    u16* sAw = sA[buf] + wv * 512;                      // wave staging base (1KB/wave)
    u16* sBw = sB[buf] + wv * 512;
    async16(gA + k0,                   sAw);
    async16(gA + k0 + (long)32 * 4608, sAw + 32 * 64);
    async16(gA + k0 + (long)64 * 4608, sAw + 64 * 64);
    async16(gA + k0 + (long)96 * 4608, sAw + 96 * 64);
    async16(gB,             sBw);
    async16(gB + 32 * 512,  sBw + 32 * 64);
    async16(gB + 64 * 512,  sBw + 64 * 64);
    async16(gB + 96 * 512,  sBw + 96 * 64);
  };

  // prologue: depth-2 — tiles 0 and 1 both in flight (16 VMEM ops/wave)
  stage(0, 0);
  stage(1, 1);

  for (int ks = 0; ks < 72; ++ks) {
    const int cur = ks & 1;
    // wait ONLY tile ks's 8 loads (oldest); tile ks+1's 8 remain in flight
    if (ks < 71) { asm volatile("s_waitcnt vmcnt(8)" ::: "memory"); }
    else         { asm volatile("s_waitcnt vmcnt(0)" ::: "memory"); }
    __builtin_amdgcn_s_barrier();                       // raw: no implicit vmcnt(0) drain
    asm volatile("" ::: "memory");
    const u16* rowA = sA[cur] + (mh + l15) * 64;
    const u16* rowB = sB[cur] + (nh + l15) * 64;
    __builtin_amdgcn_s_setprio(1);
    #pragma unroll
    for (int h = 0; h < 2; ++h) {
      const int segA = ((h * 4 + q) ^ s7) * 8;          // un-swizzle: seg idx h*4+q
      bf16x8 af[4], bf[4];
      #pragma unroll
      for (int mi = 0; mi < 4; ++mi) af[mi] = *(const bf16x8*)(rowA + mi * 1024 + segA);
      #pragma unroll
      for (int ni = 0; ni < 4; ++ni) bf[ni] = *(const bf16x8*)(rowB + ni * 1024 + segA);
      #pragma unroll
      for (int mi = 0; mi < 4; ++mi)
        #pragma unroll
        for (int ni = 0; ni < 4; ++ni)
          acc[mi][ni] = __builtin_amdgcn_mfma_f32_16x16x32_bf16(af[mi], bf[ni], acc[mi][ni], 0, 0, 0);
    }
    __builtin_amdgcn_s_setprio(0);
    asm volatile("" ::: "memory");
    __builtin_amdgcn_s_barrier();                       // all waves done reading buf[cur]
    asm volatile("" ::: "memory");
    if (ks + 2 < 72) stage(ks + 2, cur);                // refill the buffer just consumed
  }

  u16* fb = feat + (long)b * NPAD * 512;
  #pragma unroll
  for (int mi = 0; mi < 4; ++mi) {
    const int ol = mh + mi * 16 + q * 4;
    #pragma unroll
    for (int ni = 0; ni < 4; ++ni) {
      const int p = n0 + nh + ni * 16 + l15;
      unsigned long long pk = 0;
      #pragma unroll
      for (int r = 0; r < 4; ++r) {
        float v = acc[mi][ni][r] + sBias[ol + r];
        v = v > 0.f ? v : 0.f;
        pk |= ((unsigned long long)f2b(v)) << (16 * r);
      }
      *(unsigned long long*)(fb + (long)p * 512 + m0 + ol) = pk;
    }
  }
}

// ---------------- k_head: LDS-free MFMA, dual-dtype store (flag from ws) ----------------
__global__ __launch_bounds__(256) void k_head(const u16* __restrict__ feat, const u16* __restrict__ wH,
                                              const float* __restrict__ bAll, void* __restrict__ out,
                                              const int* __restrict__ flag) {
  const int f32 = *flag;
  const int t = threadIdx.x;
  const int lane = t & 63, wv = t >> 6;
  const int l15 = lane & 15, q = lane >> 4;
  const int slot = blockIdx.x * 64 + wv * 16;          // 64 p-slots per block; NPAD%64==0
  const int b = slot / NPAD, p0 = slot - b * NPAD;
  const u16* fp = feat + ((long)b * NPAD + p0 + l15) * 512 + q * 8;
  const u16* ap = wH + (long)l15 * 512 + q * 8;
  f32x4 acc[3] = {};
  #pragma unroll
  for (int ks = 0; ks < 16; ++ks) {
    const int k0 = ks * 32;
    bf16x8 bf = *(const bf16x8*)(fp + k0);
    bf16x8 a0 = *(const bf16x8*)(ap + k0);
    bf16x8 a1 = *(const bf16x8*)(ap + 16 * 512 + k0);
    bf16x8 a2 = *(const bf16x8*)(ap + 32 * 512 + k0);
    acc[0] = __builtin_amdgcn_mfma_f32_16x16x32_bf16(a0, bf, acc[0], 0, 0, 0);
    acc[1] = __builtin_amdgcn_mfma_f32_16x16x32_bf16(a1, bf, acc[1], 0, 0, 0);
    acc[2] = __builtin_amdgcn_mfma_f32_16x16x32_bf16(a2, bf, acc[2], 0, 0, 0);
  }
  const int p = p0 + l15;
  const int pr = p / 102, pc = p - pr * 102;
  if (pr < 1 || pr > 100 || pc < 1 || pc > 100) return;  // pad position
  const int h = pr - 1, w = pc - 1;
  #pragma unroll
  for (int mi = 0; mi < 3; ++mi) {
    #pragma unroll
    for (int r = 0; r < 4; ++r) {
      const int a = mi * 16 + q * 4 + r;
      if (a >= 45) continue;
      float v = acc[mi][r] + bAll[512 + a];
      long oidx;
      if (a < 9) oidx = ((long)(b * 9 + a)) * 10000 + h * 100 + w;
      else       oidx = 720000 + ((long)(b * 36 + (a - 9))) * 10000 + h * 100 + w;
      if (f32) ((float*)out)[oidx] = v;
      else     ((u16*)out)[oidx] = f2b(v);
    }
  }
}

extern "C" void kernel_launch(void* const* d_in, const int* in_sizes, int n_in,
                              void* d_out, int out_size, void* d_ws, size_t ws_size,
                              hipStream_t stream) {
  const void* x      = d_in[0];
  const void* w_rpn  = d_in[1];
  const void* b_rpn  = d_in[2];
  const void* w_cls  = d_in[3];
  const void* b_cls  = d_in[4];
  const void* w_bbox = d_in[5];
  const void* b_bbox = d_in[6];
  char* ws = (char*)d_ws;
  u16*  xt   = (u16*) (ws);                 // 8*10752*512*2 = 88,080,384
  u16*  feat = (u16*) (ws + 88080384);      // 8*10496*512*2 = 85,983,232
  u16*  wA   = (u16*) (ws + 174063616);     // 512*4608*2    =  4,718,592
  u16*  wH   = (u16*) (ws + 178782208);     // 48*512*2      =     49,152
  float* bAll= (float*)(ws + 178831360);    // 560*4
  int*  flag = (int*) (ws + 178833600);     // 4

  k_prep<<<9024, 256, 0, stream>>>(x, w_rpn, b_rpn, w_cls, b_cls, w_bbox, b_bbox,
                                   xt, wA, wH, bAll, flag);
  k_conv<<<2624, 256, 0, stream>>>(xt, wA, bAll, feat);
  k_head<<<1312, 256, 0, stream>>>(feat, wH, bAll, d_out, flag);
}

// Round 7
// 691.068 us; speedup vs baseline: 1.1117x; 1.1053x over previous
//
#include <hip/hip_runtime.h>
#include <stdint.h>

typedef unsigned short u16;
typedef __bf16 bf16x8 __attribute__((ext_vector_type(8)));
typedef float f32x4 __attribute__((ext_vector_type(4)));

// Geometry
// x: [8, 512, 100, 100] NCHW (dtype runtime-detected: f32 or bf16). Padded grid 102x102.
// xt: channels-last padded input [b][row][c] bf16, row = 128-guard + p, per-batch stride 10752 rows.
// feat: [b][p][o] bf16, per-batch stride 10496 rows.
// wA: [o][cchunk*576 + s*64 + c_in]  (K-order: c-chunk major, shift s, 64 c_in)
#define XT_STRIDE 10752
#define XT_GUARD  128
#define NPAD      10496
#define NT        82

__device__ __forceinline__ float b2f(u16 u) {
  union { unsigned int i; float f; } v; v.i = ((unsigned int)u) << 16; return v.f;
}
__device__ __forceinline__ u16 f2b(float f) {
  union { float f; unsigned int i; } v; v.f = f;
  unsigned int u = v.i;
  unsigned int r = u + 0x7FFFu + ((u >> 16) & 1u);  // RNE, finite inputs
  return (u16)(r >> 16);
}
__device__ __forceinline__ float ldin(const void* p, long i, int f32) {
  return f32 ? ((const float*)p)[i] : b2f(((const u16*)p)[i]);
}
// async global->LDS, 16B per lane; LDS dest = wave-uniform base + lane*16
__device__ __forceinline__ void async16(const void* g, void* l) {
  __builtin_amdgcn_global_load_lds(
      (const __attribute__((address_space(1))) unsigned int*)g,
      (__attribute__((address_space(3))) unsigned int*)l, 16, 0, 0);
}
// Wave-level dtype sniff: all waves scan the SAME 16KB window of x -> identical verdict.
__device__ __forceinline__ int sniff_is_f32(const void* x) {
  const uint4* p = (const uint4*)x;
  const int lane = threadIdx.x & 63;
  unsigned int acc = 0;
  #pragma unroll
  for (int i = 0; i < 16; ++i) {
    uint4 v = p[i * 64 + lane];
    unsigned int w0 = v.x, w1 = v.y, w2 = v.z, w3 = v.w;
    acc |= ((w0 & 0x7F80u) == 0x7F80u) | (((w0 >> 16) & 0x7F80u) == 0x7F80u);
    acc |= ((w1 & 0x7F80u) == 0x7F80u) | (((w1 >> 16) & 0x7F80u) == 0x7F80u);
    acc |= ((w2 & 0x7F80u) == 0x7F80u) | (((w2 >> 16) & 0x7F80u) == 0x7F80u);
    acc |= ((w3 & 0x7F80u) == 0x7F80u) | (((w3 >> 16) & 0x7F80u) == 0x7F80u);
  }
  return __any(acc != 0) ? 1 : 0;
}

// ---------------- k_prep: fused zero-pads + transpose + wA-shuffle + wH/bias pack ----------------
// Roles by block range (independent, disjoint writes):
//   [0,6400): transpose  (b 8 x h 100 x cb 8)
//   [6400,7904): zero xt pad/guard cells (8 x 188)
//   [7904,8928): wA shuffle (1024)
//   [8928,9024): wH + biases (96); block 8928 publishes dtype flag for k_head
__global__ __launch_bounds__(256) void k_prep(const void* __restrict__ x,
                                              const void* __restrict__ w_rpn,
                                              const void* __restrict__ b_rpn,
                                              const void* __restrict__ w_cls,
                                              const void* __restrict__ b_cls,
                                              const void* __restrict__ w_bbox,
                                              const void* __restrict__ b_bbox,
                                              u16* __restrict__ xt,
                                              u16* __restrict__ wA,
                                              u16* __restrict__ wH,
                                              float* __restrict__ bAll,
                                              int* __restrict__ flagOut) {
  const int blk = blockIdx.x;
  const int t = threadIdx.x;
  if (blk < 6400) {
    // ---- transpose: unit = 8 channels x 4 w; reg transpose, 16B stores ----
    const int f32 = sniff_is_f32(x);
    if (t >= 200) return;
    const int b = blk / 800, r = blk - b * 800;
    const int h = r >> 3, cb = r & 7;
    const int co = t / 25, jw = t % 25;
    const int c0 = cb * 64 + co * 8;
    u16 v[8][4];
    if (!f32) {
      const u16* src = (const u16*)x + (long)(b * 512 + c0) * 10000 + h * 100 + jw * 4;
      #pragma unroll
      for (int dc = 0; dc < 8; ++dc) {
        uint2 u = *(const uint2*)(src + (long)dc * 10000);
        const u16* pv = (const u16*)&u;
        v[dc][0] = pv[0]; v[dc][1] = pv[1]; v[dc][2] = pv[2]; v[dc][3] = pv[3];
      }
    } else {
      const float* src = (const float*)x + (long)(b * 512 + c0) * 10000 + h * 100 + jw * 4;
      #pragma unroll
      for (int dc = 0; dc < 8; ++dc) {
        float4 u = *(const float4*)(src + (long)dc * 10000);
        v[dc][0] = f2b(u.x); v[dc][1] = f2b(u.y); v[dc][2] = f2b(u.z); v[dc][3] = f2b(u.w);
      }
    }
    u16* dst = xt + ((long)b * XT_STRIDE + XT_GUARD + (h + 1) * 102 + 1 + jw * 4) * 512 + c0;
    #pragma unroll
    for (int dw = 0; dw < 4; ++dw) {
      union { uint4 u; u16 s[8]; } pk;
      #pragma unroll
      for (int dc = 0; dc < 8; ++dc) pk.s[dc] = v[dc][dw];
      *(uint4*)(dst + (long)dw * 512) = pk.u;
    }
  } else if (blk < 7904) {
    // ---- zero pad/guard cells of xt (48128 uint4 units per batch) ----
    const int i2 = blk - 6400;
    const int b = i2 / 188, bx = i2 - b * 188;
    const int i = bx * 256 + t;
    if (i >= 48128) return;
    int row, sub;
    if (i < 35328) {
      int rr = i >> 6; sub = i & 63;
      row = (rr < 230) ? rr : (10200 + rr);  // [0,230) or [10430,10752)
    } else {
      int j = i - 35328;
      int ci = j >> 6; sub = j & 63;
      int pr = (ci >> 1) + 1;
      row = XT_GUARD + pr * 102 + (ci & 1) * 101;
    }
    uint4 z = {0, 0, 0, 0};
    *(uint4*)(xt + ((long)b * XT_STRIDE + row) * 512 + sub * 8) = z;
  } else if (blk < 8928) {
    // ---- wA: [o][c][3][3] -> [o][cchunk*576 + s*64 + c_in]  (s-fastest K order) ----
    const int f32 = sniff_is_f32(x);
    const int idx = (blk - 7904) * 256 + t;     // o*512+c
    const int o = idx >> 9, c = idx & 511;
    u16* dst = wA + (long)o * 4608 + (c >> 6) * 576 + (c & 63);
    #pragma unroll
    for (int s = 0; s < 9; ++s) dst[s * 64] = f2b(ldin(w_rpn, (long)idx * 9 + s, f32));
  } else {
    // ---- wH [48][512] (45 real + 3 zero rows) + biases + flag publish ----
    const int f32 = sniff_is_f32(x);
    const int idx = (blk - 8928) * 256 + t;     // < 24576
    const int a = idx >> 9, c = idx & 511;
    float v = 0.f;
    if (a < 9) v = ldin(w_cls, a * 512 + c, f32);
    else if (a < 45) v = ldin(w_bbox, (a - 9) * 512 + c, f32);
    wH[idx] = f2b(v);
    if (idx < 512) bAll[idx] = ldin(b_rpn, idx, f32);
    if (c == 0) {
      float bv = 0.f;
      if (a < 9) bv = ldin(b_cls, a, f32);
      else if (a < 45) bv = ldin(b_bbox, a - 9, f32);
      bAll[512 + a] = bv;
    }
    if (blk == 8928 && t == 0) *flagOut = f32;
  }
}

// ---------------- Conv implicit GEMM: 128x128 tile, 2 waves x (128x64), BK=64 ----------------
// Structure = the 366us champion EXACTLY (single-buffer convoy: stage -> vmcnt(0) -> barrier ->
// MFMA -> barrier; 4 blocks/CU co-residency does the latency smoothing; 16x16x32 MFMA;
// l15-row + XOR-seg conflict-free LDS; s-fastest K for L2-resident B; XCD swizzle).
// ONE change: 2 waves x (128x64 output) instead of 4 x (64x64).
//   LDS-pipe model (calibrated on R0/R3/R5/R6): champion block-step = 64 ds_read_b128 x 12cy
//   + 32KB writes/128B = 1024 cy LDS vs 621 cy MFMA -> LDS-bound, util cap 52% (measured 52.5).
//   This: 48 reads + same writes = 834 cy LDS vs 621 MFMA -> cap ~74%, wall/block-step ~950-1000.
// Registers: acc 8x4xf32x4 = 128 AGPR + ~88 VGPR = 216 unified -> 2 waves/SIMD; 4 blocks x 2
// waves = 8 waves/CU (reg-feasible AND LDS-feasible: 4 x 33KB = 133KB). Occupancy unchanged at
// 4 blocks/CU -- the thing R3/R5/R6 each lost.
__global__ __launch_bounds__(128, 2) void k_conv(const u16* __restrict__ xt, const u16* __restrict__ wA,
                                                 const float* __restrict__ bAll, u16* __restrict__ feat) {
  __shared__ u16 sA[128 * 64];   // 16 KB
  __shared__ u16 sB[128 * 64];   // 16 KB
  __shared__ float sBias[128];
  const int t = threadIdx.x;           // 0..127
  const int i = blockIdx.x;            // 0..2623
  const int xcd = i & 7, j = i >> 3;   // j: 0..327
  const int mtb = j / 82, nt = j - mtb * 82;
  const int pair = xcd + 8 * mtb;      // 0..31
  const int mt = pair & 3, b = pair >> 2;
  const int m0 = mt * 128, n0 = nt * 128;
  sBias[t] = bAll[m0 + t];
  f32x4 acc[8][4] = {};
  const int lane = t & 63, wv = t >> 6;        // 2 waves; wave owns full M x 64-col n-half
  const int srow = t >> 3;                     // staging row 0..15 (+16 per call)
  const int sseg = (((t & 7) ^ (srow & 7))) * 8;  // XOR-permuted source segment
  const int l15 = lane & 15, q = lane >> 4;
  const int s7 = l15 & 7;                      // reader XOR key (row&7)
  const u16* gA = wA + (long)(m0 + srow) * 4608 + sseg;
  const u16* xtb = xt + ((long)b * XT_STRIDE + XT_GUARD) * 512;
  u16* sAw = sA + wv * 512;                    // wave staging base (1KB/wave per call)
  u16* sBw = sB + wv * 512;
  const u16* rowA = sA + l15 * 64;             // A frag row base (+ mi*1024 + seg)
  const u16* rowB = sB + (wv * 64 + l15) * 64; // B frag row base (+ ni*1024 + seg)
  for (int ks = 0; ks < 72; ++ks) {
    const int k0 = ks * 64;
    const int cchunk = ks / 9;
    const int s = ks - cchunk * 9;                      // shift 0..8, FASTEST
    const int c0 = cchunk * 64;
    const int off = (s / 3) * 102 + (s - (s / 3) * 3) - 103;  // (dh-1)*102 + (dw-1)
    const u16* gB = xtb + (long)(n0 + srow + off) * 512 + c0 + sseg;
    #pragma unroll
    for (int ci = 0; ci < 8; ++ci)
      async16(gA + k0 + (long)ci * 16 * 4608, sAw + ci * 1024);
    #pragma unroll
    for (int ci = 0; ci < 8; ++ci)
      async16(gB + (long)ci * 16 * 512, sBw + ci * 1024);
    asm volatile("s_waitcnt vmcnt(0)" ::: "memory");    // drain async-LDS before barrier
    __syncthreads();
    #pragma unroll
    for (int h = 0; h < 2; ++h) {
      const int segA = ((h * 4 + q) ^ s7) * 8;          // un-swizzle: logical seg h*4+q
      bf16x8 af[8], bf[4];
      #pragma unroll
      for (int mi = 0; mi < 8; ++mi) af[mi] = *(const bf16x8*)(rowA + mi * 1024 + segA);
      #pragma unroll
      for (int ni = 0; ni < 4; ++ni) bf[ni] = *(const bf16x8*)(rowB + ni * 1024 + segA);
      #pragma unroll
      for (int mi = 0; mi < 8; ++mi)
        #pragma unroll
        for (int ni = 0; ni < 4; ++ni)
          acc[mi][ni] = __builtin_amdgcn_mfma_f32_16x16x32_bf16(af[mi], bf[ni], acc[mi][ni], 0, 0, 0);
    }
    __syncthreads();
  }
  // ---- epilogue: bias + ReLU + bf16 pack, 8B stores ----
  u16* fb = feat + (long)b * NPAD * 512;
  #pragma unroll
  for (int mi = 0; mi < 8; ++mi) {
    const int ol = mi * 16 + q * 4;
    #pragma unroll
    for (int ni = 0; ni < 4; ++ni) {
      const int p = n0 + wv * 64 + ni * 16 + l15;
      unsigned long long pk = 0;
      #pragma unroll
      for (int r = 0; r < 4; ++r) {
        float v = acc[mi][ni][r] + sBias[ol + r];
        v = v > 0.f ? v : 0.f;
        pk |= ((unsigned long long)f2b(v)) << (16 * r);
      }
      *(unsigned long long*)(fb + (long)p * 512 + m0 + ol) = pk;
    }
  }
}

// ---------------- k_head: LDS-free MFMA, dual-dtype store (flag from ws) ----------------
__global__ __launch_bounds__(256) void k_head(const u16* __restrict__ feat, const u16* __restrict__ wH,
                                              const float* __restrict__ bAll, void* __restrict__ out,
                                              const int* __restrict__ flag) {
  const int f32 = *flag;
  const int t = threadIdx.x;
  const int lane = t & 63, wv = t >> 6;
  const int l15 = lane & 15, q = lane >> 4;
  const int slot = blockIdx.x * 64 + wv * 16;          // 64 p-slots per block; NPAD%64==0
  const int b = slot / NPAD, p0 = slot - b * NPAD;
  const u16* fp = feat + ((long)b * NPAD + p0 + l15) * 512 + q * 8;
  const u16* ap = wH + (long)l15 * 512 + q * 8;
  f32x4 acc[3] = {};
  #pragma unroll
  for (int ks = 0; ks < 16; ++ks) {
    const int k0 = ks * 32;
    bf16x8 bf = *(const bf16x8*)(fp + k0);
    bf16x8 a0 = *(const bf16x8*)(ap + k0);
    bf16x8 a1 = *(const bf16x8*)(ap + 16 * 512 + k0);
    bf16x8 a2 = *(const bf16x8*)(ap + 32 * 512 + k0);
    acc[0] = __builtin_amdgcn_mfma_f32_16x16x32_bf16(a0, bf, acc[0], 0, 0, 0);
    acc[1] = __builtin_amdgcn_mfma_f32_16x16x32_bf16(a1, bf, acc[1], 0, 0, 0);
    acc[2] = __builtin_amdgcn_mfma_f32_16x16x32_bf16(a2, bf, acc[2], 0, 0, 0);
  }
  const int p = p0 + l15;
  const int pr = p / 102, pc = p - pr * 102;
  if (pr < 1 || pr > 100 || pc < 1 || pc > 100) return;  // pad position
  const int h = pr - 1, w = pc - 1;
  #pragma unroll
  for (int mi = 0; mi < 3; ++mi) {
    #pragma unroll
    for (int r = 0; r < 4; ++r) {
      const int a = mi * 16 + q * 4 + r;
      if (a >= 45) continue;
      float v = acc[mi][r] + bAll[512 + a];
      long oidx;
      if (a < 9) oidx = ((long)(b * 9 + a)) * 10000 + h * 100 + w;
      else       oidx = 720000 + ((long)(b * 36 + (a - 9))) * 10000 + h * 100 + w;
      if (f32) ((float*)out)[oidx] = v;
      else     ((u16*)out)[oidx] = f2b(v);
    }
  }
}

extern "C" void kernel_launch(void* const* d_in, const int* in_sizes, int n_in,
                              void* d_out, int out_size, void* d_ws, size_t ws_size,
                              hipStream_t stream) {
  const void* x      = d_in[0];
  const void* w_rpn  = d_in[1];
  const void* b_rpn  = d_in[2];
  const void* w_cls  = d_in[3];
  const void* b_cls  = d_in[4];
  const void* w_bbox = d_in[5];
  const void* b_bbox = d_in[6];
  char* ws = (char*)d_ws;
  u16*  xt   = (u16*) (ws);                 // 8*10752*512*2 = 88,080,384
  u16*  feat = (u16*) (ws + 88080384);      // 8*10496*512*2 = 85,983,232
  u16*  wA   = (u16*) (ws + 174063616);     // 512*4608*2    =  4,718,592
  u16*  wH   = (u16*) (ws + 178782208);     // 48*512*2      =     49,152
  float* bAll= (float*)(ws + 178831360);    // 560*4
  int*  flag = (int*) (ws + 178833600);     // 4

  k_prep<<<9024, 256, 0, stream>>>(x, w_rpn, b_rpn, w_cls, b_cls, w_bbox, b_bbox,
                                   xt, wA, wH, bAll, flag);
  k_conv<<<2624, 128, 0, stream>>>(xt, wA, bAll, feat);
  k_head<<<1312, 256, 0, stream>>>(feat, wH, bAll, d_out, flag);
}

// Round 9
// 655.374 us; speedup vs baseline: 1.1722x; 1.0545x over previous
//
#include <hip/hip_runtime.h>
#include <stdint.h>

typedef unsigned short u16;
typedef __bf16 bf16x8 __attribute__((ext_vector_type(8)));
typedef float f32x4 __attribute__((ext_vector_type(4)));

// Geometry
// x: [8, 512, 100, 100] NCHW (dtype runtime-detected: f32 or bf16). Padded grid 102x102.
// xt: channels-last padded input [b][row][c] bf16, row = 128-guard + p, per-batch stride 10752 rows.
// feat: [b][p][o] bf16, per-batch stride 10496 rows.
// wA: [o][cchunk*576 + s*64 + c_in]  (K-order: c-chunk major, shift s, 64 c_in)
#define XT_STRIDE 10752
#define XT_GUARD  128
#define NPAD      10496
#define NT        82

__device__ __forceinline__ float b2f(u16 u) {
  union { unsigned int i; float f; } v; v.i = ((unsigned int)u) << 16; return v.f;
}
__device__ __forceinline__ u16 f2b(float f) {
  union { float f; unsigned int i; } v; v.f = f;
  unsigned int u = v.i;
  unsigned int r = u + 0x7FFFu + ((u >> 16) & 1u);  // RNE, finite inputs
  return (u16)(r >> 16);
}
__device__ __forceinline__ float ldin(const void* p, long i, int f32) {
  return f32 ? ((const float*)p)[i] : b2f(((const u16*)p)[i]);
}
// async global->LDS, 16B per lane; LDS dest = wave-uniform base + lane*16
__device__ __forceinline__ void async16(const void* g, void* l) {
  __builtin_amdgcn_global_load_lds(
      (const __attribute__((address_space(1))) unsigned int*)g,
      (__attribute__((address_space(3))) unsigned int*)l, 16, 0, 0);
}
// Wave-level dtype sniff (64 lanes scan a 16KB window of x).
__device__ __forceinline__ int sniff_is_f32(const void* x) {
  const uint4* p = (const uint4*)x;
  const int lane = threadIdx.x & 63;
  unsigned int acc = 0;
  #pragma unroll
  for (int i = 0; i < 16; ++i) {
    uint4 v = p[i * 64 + lane];
    unsigned int w0 = v.x, w1 = v.y, w2 = v.z, w3 = v.w;
    acc |= ((w0 & 0x7F80u) == 0x7F80u) | (((w0 >> 16) & 0x7F80u) == 0x7F80u);
    acc |= ((w1 & 0x7F80u) == 0x7F80u) | (((w1 >> 16) & 0x7F80u) == 0x7F80u);
    acc |= ((w2 & 0x7F80u) == 0x7F80u) | (((w2 >> 16) & 0x7F80u) == 0x7F80u);
    acc |= ((w3 & 0x7F80u) == 0x7F80u) | (((w3 >> 16) & 0x7F80u) == 0x7F80u);
  }
  return __any(acc != 0) ? 1 : 0;
}

// ---------------- k_sniff: one-wave dtype detection, publishes flag for all later kernels --------
__global__ __launch_bounds__(64) void k_sniff(const void* __restrict__ x, int* __restrict__ flagOut) {
  const int f32 = sniff_is_f32(x);
  if (threadIdx.x == 0) *flagOut = f32;
}

// ---------------- k_prep: fused zero-pads + transpose + wA-shuffle + wH/bias pack ----------------
// Roles by block range (independent, disjoint writes):
//   [0,6400): transpose  (b 8 x h 100 x cb 8)
//   [6400,7904): zero xt pad/guard cells (8 x 188)
//   [7904,8928): wA shuffle (1024)
//   [8928,9024): wH + biases (96)
// dtype flag comes from k_sniff (launched before on the same stream).
__global__ __launch_bounds__(256) void k_prep(const void* __restrict__ x,
                                              const void* __restrict__ w_rpn,
                                              const void* __restrict__ b_rpn,
                                              const void* __restrict__ w_cls,
                                              const void* __restrict__ b_cls,
                                              const void* __restrict__ w_bbox,
                                              const void* __restrict__ b_bbox,
                                              u16* __restrict__ xt,
                                              u16* __restrict__ wA,
                                              u16* __restrict__ wH,
                                              float* __restrict__ bAll,
                                              const int* __restrict__ flag) {
  const int blk = blockIdx.x;
  const int t = threadIdx.x;
  if (blk < 6400) {
    // ---- transpose: unit = 8 channels x 4 w; reg transpose, 16B stores ----
    // Lane mapping co=t&7 (c fastest), jw=t>>3: 8 consecutive lanes cover 64 consecutive
    // channels -> stores coalesce into 128B segments (was 16B scatter with co=t/25).
    // Loads unaffected: stride-8 lane groups still cover contiguous 400B source rows
    // (HW coalesces by address set, not lane order).
    const int f32 = *flag;
    if (t >= 200) return;
    const int b = blk / 800, r = blk - b * 800;
    const int h = r >> 3, cb = r & 7;
    const int co = t & 7, jw = t >> 3;
    const int c0 = cb * 64 + co * 8;
    u16 v[8][4];
    if (!f32) {
      const u16* src = (const u16*)x + (long)(b * 512 + c0) * 10000 + h * 100 + jw * 4;
      #pragma unroll
      for (int dc = 0; dc < 8; ++dc) {
        uint2 u = *(const uint2*)(src + (long)dc * 10000);
        const u16* pv = (const u16*)&u;
        v[dc][0] = pv[0]; v[dc][1] = pv[1]; v[dc][2] = pv[2]; v[dc][3] = pv[3];
      }
    } else {
      const float* src = (const float*)x + (long)(b * 512 + c0) * 10000 + h * 100 + jw * 4;
      #pragma unroll
      for (int dc = 0; dc < 8; ++dc) {
        float4 u = *(const float4*)(src + (long)dc * 10000);
        v[dc][0] = f2b(u.x); v[dc][1] = f2b(u.y); v[dc][2] = f2b(u.z); v[dc][3] = f2b(u.w);
      }
    }
    u16* dst = xt + ((long)b * XT_STRIDE + XT_GUARD + (h + 1) * 102 + 1 + jw * 4) * 512 + c0;
    #pragma unroll
    for (int dw = 0; dw < 4; ++dw) {
      union { uint4 u; u16 s[8]; } pk;
      #pragma unroll
      for (int dc = 0; dc < 8; ++dc) pk.s[dc] = v[dc][dw];
      *(uint4*)(dst + (long)dw * 512) = pk.u;
    }
  } else if (blk < 7904) {
    // ---- zero pad/guard cells of xt (48128 uint4 units per batch) ----
    const int i2 = blk - 6400;
    const int b = i2 / 188, bx = i2 - b * 188;
    const int i = bx * 256 + t;
    if (i >= 48128) return;
    int row, sub;
    if (i < 35328) {
      int rr = i >> 6; sub = i & 63;
      row = (rr < 230) ? rr : (10200 + rr);  // [0,230) or [10430,10752)
    } else {
      int j = i - 35328;
      int ci = j >> 6; sub = j & 63;
      int pr = (ci >> 1) + 1;
      row = XT_GUARD + pr * 102 + (ci & 1) * 101;
    }
    uint4 z = {0, 0, 0, 0};
    *(uint4*)(xt + ((long)b * XT_STRIDE + row) * 512 + sub * 8) = z;
  } else if (blk < 8928) {
    // ---- wA: [o][c][3][3] -> [o][cchunk*576 + s*64 + c_in]  (s-fastest K order) ----
    const int f32 = *flag;
    const int idx = (blk - 7904) * 256 + t;     // o*512+c
    const int o = idx >> 9, c = idx & 511;
    u16* dst = wA + (long)o * 4608 + (c >> 6) * 576 + (c & 63);
    #pragma unroll
    for (int s = 0; s < 9; ++s) dst[s * 64] = f2b(ldin(w_rpn, (long)idx * 9 + s, f32));
  } else {
    // ---- wH [48][512] (45 real + 3 zero rows) + biases ----
    const int f32 = *flag;
    const int idx = (blk - 8928) * 256 + t;     // < 24576
    const int a = idx >> 9, c = idx & 511;
    float v = 0.f;
    if (a < 9) v = ldin(w_cls, a * 512 + c, f32);
    else if (a < 45) v = ldin(w_bbox, (a - 9) * 512 + c, f32);
    wH[idx] = f2b(v);
    if (idx < 512) bAll[idx] = ldin(b_rpn, idx, f32);
    if (c == 0) {
      float bv = 0.f;
      if (a < 9) bv = ldin(b_cls, a, f32);
      else if (a < 45) bv = ldin(b_bbox, a - 9, f32);
      bAll[512 + a] = bv;
    }
  }
}

// ---------------- Conv implicit GEMM: 128x128 tile, BK=64, XCD swizzle, XOR-seg LDS ----------------
// THE 366us CHAMPION, verbatim (R0). K-order: c-chunk major, shift s FASTEST -> the 9 s-iterations
// of a c-chunk re-read the same ~40KB xt window in consecutive iterations => L2-resident.
// Seven structural experiments (R1-R7: 8-phase 256², 32x32 MFMA, 256x128, prefetch-dbuf,
// depth-2 counted vmcnt, 2-wave 128x64) all regressed: throughput tracks resident waves/CU
// (~12 here) and every restructure paid occupancy for its gain. This convoy at 4 blocks/CU
// co-residency is the measured local optimum for this tile family.
__global__ __launch_bounds__(256, 4) void k_conv(const u16* __restrict__ xt, const u16* __restrict__ wA,
                                                 const float* __restrict__ bAll, u16* __restrict__ feat) {
  __shared__ u16 sA[128 * 64];   // 16 KB
  __shared__ u16 sB[128 * 64];   // 16 KB
  __shared__ float sBias[128];
  const int t = threadIdx.x;
  const int i = blockIdx.x;            // 0..2623
  const int xcd = i & 7, j = i >> 3;   // j: 0..327
  const int mtb = j / 82, nt = j - mtb * 82;
  const int pair = xcd + 8 * mtb;      // 0..31
  const int mt = pair & 3, b = pair >> 2;
  const int m0 = mt * 128, n0 = nt * 128;
  if (t < 128) sBias[t] = bAll[m0 + t];
  f32x4 acc[4][4] = {};
  const int lane = t & 63, wv = t >> 6;
  const int srow = t >> 3;                              // staging row 0..31 (+32 per round)
  const int sseg = (((t & 7) ^ (srow & 7))) * 8;        // XOR-permuted source segment
  const int mh = (wv & 1) * 64, nh = (wv >> 1) * 64;
  const int l15 = lane & 15, q = lane >> 4;
  const int s7 = l15 & 7;                               // reader XOR key (row&7)
  u16* sAw = sA + wv * 512;                             // wave staging base (1KB/wave)
  u16* sBw = sB + wv * 512;
  const u16* gA = wA + (long)(m0 + srow) * 4608 + sseg;
  const u16* xtb = xt + ((long)b * XT_STRIDE + XT_GUARD) * 512;
  const u16* rowA = sA + (mh + l15) * 64;               // A frag row base
  const u16* rowB = sB + (nh + l15) * 64;
  for (int ks = 0; ks < 72; ++ks) {
    const int k0 = ks * 64;
    const int cchunk = ks / 9;
    const int s = ks - cchunk * 9;                      // shift 0..8, FASTEST
    const int c0 = cchunk * 64;
    const int off = (s / 3) * 102 + (s - (s / 3) * 3) - 103;  // (dh-1)*102 + (dw-1)
    const u16* gB = xtb + (long)(n0 + srow + off) * 512 + c0 + sseg;
    async16(gA + k0, sAw);
    async16(gA + k0 + (long)32 * 4608, sAw + 32 * 64);
    async16(gA + k0 + (long)64 * 4608, sAw + 64 * 64);
    async16(gA + k0 + (long)96 * 4608, sAw + 96 * 64);
    async16(gB,             sBw);
    async16(gB + 32 * 512,  sBw + 32 * 64);
    async16(gB + 64 * 512,  sBw + 64 * 64);
    async16(gB + 96 * 512,  sBw + 96 * 64);
    asm volatile("s_waitcnt vmcnt(0)" ::: "memory");    // drain async-LDS before barrier
    __syncthreads();
    #pragma unroll
    for (int h = 0; h < 2; ++h) {
      const int segA = ((h * 4 + q) ^ s7) * 8;          // un-swizzle: seg idx h*4+q
      bf16x8 af[4], bf[4];
      #pragma unroll
      for (int mi = 0; mi < 4; ++mi) af[mi] = *(const bf16x8*)(rowA + mi * 1024 + segA);
      #pragma unroll
      for (int ni = 0; ni < 4; ++ni) bf[ni] = *(const bf16x8*)(rowB + ni * 1024 + segA);
      #pragma unroll
      for (int mi = 0; mi < 4; ++mi)
        #pragma unroll
        for (int ni = 0; ni < 4; ++ni)
          acc[mi][ni] = __builtin_amdgcn_mfma_f32_16x16x32_bf16(af[mi], bf[ni], acc[mi][ni], 0, 0, 0);
    }
    __syncthreads();
  }
  u16* fb = feat + (long)b * NPAD * 512;
  #pragma unroll
  for (int mi = 0; mi < 4; ++mi) {
    const int ol = mh + mi * 16 + q * 4;
    #pragma unroll
    for (int ni = 0; ni < 4; ++ni) {
      const int p = n0 + nh + ni * 16 + l15;
      unsigned long long pk = 0;
      #pragma unroll
      for (int r = 0; r < 4; ++r) {
        float v = acc[mi][ni][r] + sBias[ol + r];
        v = v > 0.f ? v : 0.f;
        pk |= ((unsigned long long)f2b(v)) << (16 * r);
      }
      *(unsigned long long*)(fb + (long)p * 512 + m0 + ol) = pk;
    }
  }
}

// ---------------- k_head: LDS-free MFMA, dual-dtype store (flag from ws) ----------------
__global__ __launch_bounds__(256) void k_head(const u16* __restrict__ feat, const u16* __restrict__ wH,
                                              const float* __restrict__ bAll, void* __restrict__ out,
                                              const int* __restrict__ flag) {
  const int f32 = *flag;
  const int t = threadIdx.x;
  const int lane = t & 63, wv = t >> 6;
  const int l15 = lane & 15, q = lane >> 4;
  const int slot = blockIdx.x * 64 + wv * 16;          // 64 p-slots per block; NPAD%64==0
  const int b = slot / NPAD, p0 = slot - b * NPAD;
  const u16* fp = feat + ((long)b * NPAD + p0 + l15) * 512 + q * 8;
  const u16* ap = wH + (long)l15 * 512 + q * 8;
  f32x4 acc[3] = {};
  #pragma unroll
  for (int ks = 0; ks < 16; ++ks) {
    const int k0 = ks * 32;
    bf16x8 bf = *(const bf16x8*)(fp + k0);
    bf16x8 a0 = *(const bf16x8*)(ap + k0);
    bf16x8 a1 = *(const bf16x8*)(ap + 16 * 512 + k0);
    bf16x8 a2 = *(const bf16x8*)(ap + 32 * 512 + k0);
    acc[0] = __builtin_amdgcn_mfma_f32_16x16x32_bf16(a0, bf, acc[0], 0, 0, 0);
    acc[1] = __builtin_amdgcn_mfma_f32_16x16x32_bf16(a1, bf, acc[1], 0, 0, 0);
    acc[2] = __builtin_amdgcn_mfma_f32_16x16x32_bf16(a2, bf, acc[2], 0, 0, 0);
  }
  const int p = p0 + l15;
  const int pr = p / 102, pc = p - pr * 102;
  if (pr < 1 || pr > 100 || pc < 1 || pc > 100) return;  // pad position
  const int h = pr - 1, w = pc - 1;
  #pragma unroll
  for (int mi = 0; mi < 3; ++mi) {
    #pragma unroll
    for (int r = 0; r < 4; ++r) {
      const int a = mi * 16 + q * 4 + r;
      if (a >= 45) continue;
      float v = acc[mi][r] + bAll[512 + a];
      long oidx;
      if (a < 9) oidx = ((long)(b * 9 + a)) * 10000 + h * 100 + w;
      else       oidx = 720000 + ((long)(b * 36 + (a - 9))) * 10000 + h * 100 + w;
      if (f32) ((float*)out)[oidx] = v;
      else     ((u16*)out)[oidx] = f2b(v);
    }
  }
}

extern "C" void kernel_launch(void* const* d_in, const int* in_sizes, int n_in,
                              void* d_out, int out_size, void* d_ws, size_t ws_size,
                              hipStream_t stream) {
  const void* x      = d_in[0];
  const void* w_rpn  = d_in[1];
  const void* b_rpn  = d_in[2];
  const void* w_cls  = d_in[3];
  const void* b_cls  = d_in[4];
  const void* w_bbox = d_in[5];
  const void* b_bbox = d_in[6];
  char* ws = (char*)d_ws;
  u16*  xt   = (u16*) (ws);                 // 8*10752*512*2 = 88,080,384
  u16*  feat = (u16*) (ws + 88080384);      // 8*10496*512*2 = 85,983,232
  u16*  wA   = (u16*) (ws + 174063616);     // 512*4608*2    =  4,718,592
  u16*  wH   = (u16*) (ws + 178782208);     // 48*512*2      =     49,152
  float* bAll= (float*)(ws + 178831360);    // 560*4
  int*  flag = (int*) (ws + 178833600);     // 4

  k_sniff<<<1, 64, 0, stream>>>(x, flag);
  k_prep<<<9024, 256, 0, stream>>>(x, w_rpn, b_rpn, w_cls, b_cls, w_bbox, b_bbox,
                                   xt, wA, wH, bAll, flag);
  k_conv<<<2624, 256, 0, stream>>>(xt, wA, bAll, feat);
  k_head<<<1312, 256, 0, stream>>>(feat, wH, bAll, d_out, flag);
}

// Round 10
// 637.225 us; speedup vs baseline: 1.2056x; 1.0285x over previous
//
#include <hip/hip_runtime.h>
#include <stdint.h>

typedef unsigned short u16;
typedef __bf16 bf16x8 __attribute__((ext_vector_type(8)));
typedef float f32x4 __attribute__((ext_vector_type(4)));

// Geometry
// x: [8, 512, 100, 100] NCHW (dtype runtime-detected: f32 or bf16). Padded grid 102x102.
// xt: channels-last padded input [b][row][c] bf16, row = 128-guard + p, per-batch stride 10752 rows.
// feat: [b][p][o] bf16, per-batch stride 10496 rows.
// wA: [o][cchunk*576 + s*64 + c_in]  (K-order: c-chunk major, shift s, 64 c_in)
#define XT_STRIDE 10752
#define XT_GUARD  128
#define NPAD      10496
#define NT        82

__device__ __forceinline__ float b2f(u16 u) {
  union { unsigned int i; float f; } v; v.i = ((unsigned int)u) << 16; return v.f;
}
__device__ __forceinline__ u16 f2b(float f) {
  union { float f; unsigned int i; } v; v.f = f;
  unsigned int u = v.i;
  unsigned int r = u + 0x7FFFu + ((u >> 16) & 1u);  // RNE, finite inputs
  return (u16)(r >> 16);
}
__device__ __forceinline__ float ldin(const void* p, long i, int f32) {
  return f32 ? ((const float*)p)[i] : b2f(((const u16*)p)[i]);
}
// async global->LDS, 16B per lane; LDS dest = wave-uniform base + lane*16
__device__ __forceinline__ void async16(const void* g, void* l) {
  __builtin_amdgcn_global_load_lds(
      (const __attribute__((address_space(1))) unsigned int*)g,
      (__attribute__((address_space(3))) unsigned int*)l, 16, 0, 0);
}
// Wave-level dtype sniff (64 lanes scan a 16KB window of x).
__device__ __forceinline__ int sniff_is_f32(const void* x) {
  const uint4* p = (const uint4*)x;
  const int lane = threadIdx.x & 63;
  unsigned int acc = 0;
  #pragma unroll
  for (int i = 0; i < 16; ++i) {
    uint4 v = p[i * 64 + lane];
    unsigned int w0 = v.x, w1 = v.y, w2 = v.z, w3 = v.w;
    acc |= ((w0 & 0x7F80u) == 0x7F80u) | (((w0 >> 16) & 0x7F80u) == 0x7F80u);
    acc |= ((w1 & 0x7F80u) == 0x7F80u) | (((w1 >> 16) & 0x7F80u) == 0x7F80u);
    acc |= ((w2 & 0x7F80u) == 0x7F80u) | (((w2 >> 16) & 0x7F80u) == 0x7F80u);
    acc |= ((w3 & 0x7F80u) == 0x7F80u) | (((w3 >> 16) & 0x7F80u) == 0x7F80u);
  }
  return __any(acc != 0) ? 1 : 0;
}

// ---------------- k_sniff: one-wave dtype detection, publishes flag for all later kernels --------
__global__ __launch_bounds__(64) void k_sniff(const void* __restrict__ x, int* __restrict__ flagOut) {
  const int f32 = sniff_is_f32(x);
  if (threadIdx.x == 0) *flagOut = f32;
}

// ---------------- k_prep: fused zero-pads + transpose + wA-shuffle + wH/bias pack ----------------
// Roles by block range (independent, disjoint writes):
//   [0,6400): transpose  (b 8 x h 100 x cb 8)
//   [6400,7904): zero xt pad/guard cells (8 x 188)
//   [7904,8928): wA shuffle (1024)
//   [8928,9024): wH + biases (96)
// dtype flag comes from k_sniff (launched before on the same stream).
__global__ __launch_bounds__(256) void k_prep(const void* __restrict__ x,
                                              const void* __restrict__ w_rpn,
                                              const void* __restrict__ b_rpn,
                                              const void* __restrict__ w_cls,
                                              const void* __restrict__ b_cls,
                                              const void* __restrict__ w_bbox,
                                              const void* __restrict__ b_bbox,
                                              u16* __restrict__ xt,
                                              u16* __restrict__ wA,
                                              u16* __restrict__ wH,
                                              float* __restrict__ bAll,
                                              const int* __restrict__ flag) {
  const int blk = blockIdx.x;
  const int t = threadIdx.x;
  if (blk < 6400) {
    // ---- transpose: unit = 8 channels x 4 w; reg transpose, 16B stores ----
    const int f32 = *flag;
    if (t >= 200) return;
    const int b = blk / 800, r = blk - b * 800;
    const int h = r >> 3, cb = r & 7;
    const int co = t & 7, jw = t >> 3;
    const int c0 = cb * 64 + co * 8;
    u16 v[8][4];
    if (!f32) {
      const u16* src = (const u16*)x + (long)(b * 512 + c0) * 10000 + h * 100 + jw * 4;
      #pragma unroll
      for (int dc = 0; dc < 8; ++dc) {
        uint2 u = *(const uint2*)(src + (long)dc * 10000);
        const u16* pv = (const u16*)&u;
        v[dc][0] = pv[0]; v[dc][1] = pv[1]; v[dc][2] = pv[2]; v[dc][3] = pv[3];
      }
    } else {
      const float* src = (const float*)x + (long)(b * 512 + c0) * 10000 + h * 100 + jw * 4;
      #pragma unroll
      for (int dc = 0; dc < 8; ++dc) {
        float4 u = *(const float4*)(src + (long)dc * 10000);
        v[dc][0] = f2b(u.x); v[dc][1] = f2b(u.y); v[dc][2] = f2b(u.z); v[dc][3] = f2b(u.w);
      }
    }
    u16* dst = xt + ((long)b * XT_STRIDE + XT_GUARD + (h + 1) * 102 + 1 + jw * 4) * 512 + c0;
    #pragma unroll
    for (int dw = 0; dw < 4; ++dw) {
      union { uint4 u; u16 s[8]; } pk;
      #pragma unroll
      for (int dc = 0; dc < 8; ++dc) pk.s[dc] = v[dc][dw];
      *(uint4*)(dst + (long)dw * 512) = pk.u;
    }
  } else if (blk < 7904) {
    // ---- zero pad/guard cells of xt (48128 uint4 units per batch) ----
    const int i2 = blk - 6400;
    const int b = i2 / 188, bx = i2 - b * 188;
    const int i = bx * 256 + t;
    if (i >= 48128) return;
    int row, sub;
    if (i < 35328) {
      int rr = i >> 6; sub = i & 63;
      row = (rr < 230) ? rr : (10200 + rr);  // [0,230) or [10430,10752)
    } else {
      int j = i - 35328;
      int ci = j >> 6; sub = j & 63;
      int pr = (ci >> 1) + 1;
      row = XT_GUARD + pr * 102 + (ci & 1) * 101;
    }
    uint4 z = {0, 0, 0, 0};
    *(uint4*)(xt + ((long)b * XT_STRIDE + row) * 512 + sub * 8) = z;
  } else if (blk < 8928) {
    // ---- wA: [o][c][3][3] -> [o][cchunk*576 + s*64 + c_in]  (s-fastest K order) ----
    const int f32 = *flag;
    const int idx = (blk - 7904) * 256 + t;     // o*512+c
    const int o = idx >> 9, c = idx & 511;
    u16* dst = wA + (long)o * 4608 + (c >> 6) * 576 + (c & 63);
    #pragma unroll
    for (int s = 0; s < 9; ++s) dst[s * 64] = f2b(ldin(w_rpn, (long)idx * 9 + s, f32));
  } else {
    // ---- wH [48][512] (45 real + 3 zero rows) + biases ----
    const int f32 = *flag;
    const int idx = (blk - 8928) * 256 + t;     // < 24576
    const int a = idx >> 9, c = idx & 511;
    float v = 0.f;
    if (a < 9) v = ldin(w_cls, a * 512 + c, f32);
    else if (a < 45) v = ldin(w_bbox, (a - 9) * 512 + c, f32);
    wH[idx] = f2b(v);
    if (idx < 512) bAll[idx] = ldin(b_rpn, idx, f32);
    if (c == 0) {
      float bv = 0.f;
      if (a < 9) bv = ldin(b_cls, a, f32);
      else if (a < 45) bv = ldin(b_bbox, a - 9, f32);
      bAll[512 + a] = bv;
    }
  }
}

// ---------------- Conv implicit GEMM: 128x128 tile, BK=64, B-BAND reuse across dw shifts ----------
// Champion convoy structure preserved (stage -> vmcnt(0) -> __syncthreads -> MFMA -> barrier;
// 4 blocks/CU co-residency = 16 waves/CU; 16x16x32 MFMA; l15-row XOR-seg conflict-free LDS;
// s-fastest K; XCD swizzle). ONE change: B is staged as a 130-row BAND once per dh (every 3rd
// k-step) and reused for dw=0,1,2, instead of restaging a 128-row window every step.
//   Staged bytes/block: 2304 KB -> 1552 KB (A 1152 + B 8 chunks x 3 dh x 16.6 KB = 400).
//   Convoy model (calibrated: delivery 2340cy + MFMA 2480cy per 4-block round = 51.5% predicted
//   vs 52.5 measured): delivery term scales with staged bytes -> ~1570cy -> util ~61%.
// Band geometry: rows [n0+(dh-1)*102-1, +130) in xt; max abs row 10726 < 10752, min 25, all
// initialized (payload/pad audit). Reader key = (band-local row)&7 = (l15+dw)&7 (nh,ni*16 ≡ 0
// mod 8) -- same proven XOR family as A. Stage key srow&7 ≡ row&7 (32-row stride rounds).
// LDS: A 16K + band 132x64x2 = 16.9K + bias 0.5K = 33.4 KB -> 4 blocks/CU kept.
__global__ __launch_bounds__(256, 4) void k_conv(const u16* __restrict__ xt, const u16* __restrict__ wA,
                                                 const float* __restrict__ bAll, u16* __restrict__ feat) {
  __shared__ u16 sA[128 * 64];   // 16 KB
  __shared__ u16 sB[132 * 64];   // 16.9 KB band (130 used + 2 pad rows)
  __shared__ float sBias[128];
  const int t = threadIdx.x;
  const int i = blockIdx.x;            // 0..2623
  const int xcd = i & 7, j = i >> 3;   // j: 0..327
  const int mtb = j / 82, nt = j - mtb * 82;
  const int pair = xcd + 8 * mtb;      // 0..31
  const int mt = pair & 3, b = pair >> 2;
  const int m0 = mt * 128, n0 = nt * 128;
  if (t < 128) sBias[t] = bAll[m0 + t];
  f32x4 acc[4][4] = {};
  const int lane = t & 63, wv = t >> 6;
  const int srow = t >> 3;                              // staging row 0..31 (+32 per round)
  const int sseg = (((t & 7) ^ (srow & 7))) * 8;        // XOR-permuted source segment
  const int mh = (wv & 1) * 64, nh = (wv >> 1) * 64;
  const int l15 = lane & 15, q = lane >> 4;
  const int s7 = l15 & 7;                               // A reader XOR key (row&7)
  u16* sAw = sA + wv * 512;                             // wave staging base (1KB/wave)
  const u16* gA = wA + (long)(m0 + srow) * 4608 + sseg;
  const u16* xtb = xt + ((long)b * XT_STRIDE + XT_GUARD) * 512;
  const u16* rowA = sA + (mh + l15) * 64;               // A frag row base
  for (int ks = 0; ks < 72; ++ks) {
    const int k0 = ks * 64;
    const int cchunk = ks / 9;
    const int s = ks - cchunk * 9;                      // shift 0..8, FASTEST
    const int dh = s / 3, dw = s - dh * 3;
    const int c0 = cchunk * 64;
    // A stage: every step (72 distinct K-slices)
    async16(gA + k0, sAw);
    async16(gA + k0 + (long)32 * 4608, sAw + 32 * 64);
    async16(gA + k0 + (long)64 * 4608, sAw + 64 * 64);
    async16(gA + k0 + (long)96 * 4608, sAw + 96 * 64);
    // B band stage: once per dh (dw==0); reused by dw=0,1,2. 130 rows x 64 c.
    if (dw == 0) {
      const long bs = (long)n0 + (dh - 1) * 102 - 1;    // band start row (rel. to guard base)
      const u16* gBb = xtb + (bs + srow) * 512 + c0 + sseg;
      #pragma unroll
      for (int k = 0; k < 4; ++k)                        // rows 32k + srow
        async16(gBb + (long)k * 32 * 512, sB + (k * 32 + wv * 8) * 64);
      if (t < 16)                                        // partial: rows 128,129 (wave 0 lanes)
        async16(gBb + (long)128 * 512, sB + 128 * 64);
    }
    asm volatile("s_waitcnt vmcnt(0)" ::: "memory");    // drain async-LDS before barrier
    __syncthreads();
    const int s7b = (l15 + dw) & 7;                     // B reader XOR key (band row &7)
    const u16* rowB = sB + (nh + dw + l15) * 64;        // band-local row = nh+ni*16+l15+dw
    #pragma unroll
    for (int h = 0; h < 2; ++h) {
      const int segA = ((h * 4 + q) ^ s7) * 8;          // un-swizzle: seg idx h*4+q
      const int segB = ((h * 4 + q) ^ s7b) * 8;
      bf16x8 af[4], bf[4];
      #pragma unroll
      for (int mi = 0; mi < 4; ++mi) af[mi] = *(const bf16x8*)(rowA + mi * 1024 + segA);
      #pragma unroll
      for (int ni = 0; ni < 4; ++ni) bf[ni] = *(const bf16x8*)(rowB + ni * 1024 + segB);
      #pragma unroll
      for (int mi = 0; mi < 4; ++mi)
        #pragma unroll
        for (int ni = 0; ni < 4; ++ni)
          acc[mi][ni] = __builtin_amdgcn_mfma_f32_16x16x32_bf16(af[mi], bf[ni], acc[mi][ni], 0, 0, 0);
    }
    __syncthreads();                                    // band/A safe to restage next step
  }
  u16* fb = feat + (long)b * NPAD * 512;
  #pragma unroll
  for (int mi = 0; mi < 4; ++mi) {
    const int ol = mh + mi * 16 + q * 4;
    #pragma unroll
    for (int ni = 0; ni < 4; ++ni) {
      const int p = n0 + nh + ni * 16 + l15;
      unsigned long long pk = 0;
      #pragma unroll
      for (int r = 0; r < 4; ++r) {
        float v = acc[mi][ni][r] + sBias[ol + r];
        v = v > 0.f ? v : 0.f;
        pk |= ((unsigned long long)f2b(v)) << (16 * r);
      }
      *(unsigned long long*)(fb + (long)p * 512 + m0 + ol) = pk;
    }
  }
}

// ---------------- k_head: LDS-free MFMA, dual-dtype store (flag from ws) ----------------
__global__ __launch_bounds__(256) void k_head(const u16* __restrict__ feat, const u16* __restrict__ wH,
                                              const float* __restrict__ bAll, void* __restrict__ out,
                                              const int* __restrict__ flag) {
  const int f32 = *flag;
  const int t = threadIdx.x;
  const int lane = t & 63, wv = t >> 6;
  const int l15 = lane & 15, q = lane >> 4;
  const int slot = blockIdx.x * 64 + wv * 16;          // 64 p-slots per block; NPAD%64==0
  const int b = slot / NPAD, p0 = slot - b * NPAD;
  const u16* fp = feat + ((long)b * NPAD + p0 + l15) * 512 + q * 8;
  const u16* ap = wH + (long)l15 * 512 + q * 8;
  f32x4 acc[3] = {};
  #pragma unroll
  for (int ks = 0; ks < 16; ++ks) {
    const int k0 = ks * 32;
    bf16x8 bf = *(const bf16x8*)(fp + k0);
    bf16x8 a0 = *(const bf16x8*)(ap + k0);
    bf16x8 a1 = *(const bf16x8*)(ap + 16 * 512 + k0);
    bf16x8 a2 = *(const bf16x8*)(ap + 32 * 512 + k0);
    acc[0] = __builtin_amdgcn_mfma_f32_16x16x32_bf16(a0, bf, acc[0], 0, 0, 0);
    acc[1] = __builtin_amdgcn_mfma_f32_16x16x32_bf16(a1, bf, acc[1], 0, 0, 0);
    acc[2] = __builtin_amdgcn_mfma_f32_16x16x32_bf16(a2, bf, acc[2], 0, 0, 0);
  }
  const int p = p0 + l15;
  const int pr = p / 102, pc = p - pr * 102;
  if (pr < 1 || pr > 100 || pc < 1 || pc > 100) return;  // pad position
  const int h = pr - 1, w = pc - 1;
  #pragma unroll
  for (int mi = 0; mi < 3; ++mi) {
    #pragma unroll
    for (int r = 0; r < 4; ++r) {
      const int a = mi * 16 + q * 4 + r;
      if (a >= 45) continue;
      float v = acc[mi][r] + bAll[512 + a];
      long oidx;
      if (a < 9) oidx = ((long)(b * 9 + a)) * 10000 + h * 100 + w;
      else       oidx = 720000 + ((long)(b * 36 + (a - 9))) * 10000 + h * 100 + w;
      if (f32) ((float*)out)[oidx] = v;
      else     ((u16*)out)[oidx] = f2b(v);
    }
  }
}

extern "C" void kernel_launch(void* const* d_in, const int* in_sizes, int n_in,
                              void* d_out, int out_size, void* d_ws, size_t ws_size,
                              hipStream_t stream) {
  const void* x      = d_in[0];
  const void* w_rpn  = d_in[1];
  const void* b_rpn  = d_in[2];
  const void* w_cls  = d_in[3];
  const void* b_cls  = d_in[4];
  const void* w_bbox = d_in[5];
  const void* b_bbox = d_in[6];
  char* ws = (char*)d_ws;
  u16*  xt   = (u16*) (ws);                 // 8*10752*512*2 = 88,080,384
  u16*  feat = (u16*) (ws + 88080384);      // 8*10496*512*2 = 85,983,232
  u16*  wA   = (u16*) (ws + 174063616);     // 512*4608*2    =  4,718,592
  u16*  wH   = (u16*) (ws + 178782208);     // 48*512*2      =     49,152
  float* bAll= (float*)(ws + 178831360);    // 560*4
  int*  flag = (int*) (ws + 178833600);     // 4

  k_sniff<<<1, 64, 0, stream>>>(x, flag);
  k_prep<<<9024, 256, 0, stream>>>(x, w_rpn, b_rpn, w_cls, b_cls, w_bbox, b_bbox,
                                   xt, wA, wH, bAll, flag);
  k_conv<<<2624, 256, 0, stream>>>(xt, wA, bAll, feat);
  k_head<<<1312, 256, 0, stream>>>(feat, wH, bAll, d_out, flag);
}